// Round 5
// baseline (520.017 us; speedup 1.0000x reference)
//
#include <hip/hip_runtime.h>
#include <hip/hip_bf16.h>
#include <math.h>

#define DEVI static __device__ __forceinline__

using f32x4  = __attribute__((ext_vector_type(4))) float;
using f32x16 = __attribute__((ext_vector_type(16))) float;
using s16x8  = __attribute__((ext_vector_type(8))) short;
using bf16x8 = __attribute__((ext_vector_type(8))) __bf16;
using i32x4  = __attribute__((ext_vector_type(4))) int;
using u32x2  = __attribute__((ext_vector_type(2))) unsigned int;
using u32x4  = __attribute__((ext_vector_type(4))) unsigned int;

constexpr int N   = 8192;
constexpr int KIN = 512;
constexpr int F   = 256;

DEVI unsigned f2bf(float f) {
  unsigned u = __builtin_bit_cast(unsigned, f);
  return ((u + 0x7FFFu + ((u >> 16) & 1u)) >> 16) & 0xFFFFu;
}

DEVI unsigned cvtpk(float lo, float hi) {
  unsigned r;
  asm("v_cvt_pk_bf16_f32 %0, %1, %2" : "=v"(r) : "v"(lo), "v"(hi));
  return r;
}

DEVI f32x16 mfma32(s16x8 a, s16x8 b, f32x16 c) {
  return __builtin_amdgcn_mfma_f32_32x32x16_bf16(
      __builtin_bit_cast(bf16x8, a), __builtin_bit_cast(bf16x8, b), c, 0, 0, 0);
}

DEVI void gload16(const void* g, void* lds_uniform) {
  __builtin_amdgcn_global_load_lds(
      (const __attribute__((address_space(1))) unsigned*)g,
      (__attribute__((address_space(3))) unsigned*)lds_uniform, 16, 0, 0);
}

// ---------------- cast input f32 -> bf16 (row-major [8192][512]) ----------------
__global__ __launch_bounds__(256) void k_cast(const float* __restrict__ src,
                                              unsigned short* __restrict__ dst,
                                              int n8) {
  int t = blockIdx.x * 256 + threadIdx.x;
  if (t >= n8) return;
  const f32x4* p = (const f32x4*)(src + (size_t)t * 8);
  f32x4 v0 = p[0], v1 = p[1];
  s16x8 o;
  o[0] = (short)f2bf(v0[0]); o[1] = (short)f2bf(v0[1]);
  o[2] = (short)f2bf(v0[2]); o[3] = (short)f2bf(v0[3]);
  o[4] = (short)f2bf(v1[0]); o[5] = (short)f2bf(v1[1]);
  o[6] = (short)f2bf(v1[2]); o[7] = (short)f2bf(v1[3]);
  *(s16x8*)(dst + (size_t)t * 8) = o;
}

// ---------------- W [512][256] f32 -> Wt [256][512] bf16 (transposed) -----------
__global__ __launch_bounds__(256) void k_prep_w(const float* __restrict__ W,
                                                unsigned short* __restrict__ Wt) {
  int t = blockIdx.x * 256 + threadIdx.x;   // 16384 threads
  int c = t >> 6, k0 = (t & 63) * 8;
  s16x8 o;
#pragma unroll
  for (int i = 0; i < 8; ++i) o[i] = (short)f2bf(W[(size_t)(k0 + i) * F + c]);
  *(s16x8*)(Wt + (size_t)c * KIN + k0) = o;
}

// ---------------- h = Xbf @ Wt^T : writes Ht[256][8192] bf16 + E/E5/F/F5 --------
__global__ __launch_bounds__(512) void k_gemm1(const unsigned short* __restrict__ inpb,
                                               const unsigned short* __restrict__ Wt,
                                               const float* __restrict__ a_vec,
                                               unsigned short* __restrict__ Ht,
                                               float* __restrict__ E, float* __restrict__ E5,
                                               float* __restrict__ Fv, float* __restrict__ F5v) {
  __shared__ __align__(16) char lds[4096 + 32768 + 2048];
  char* ldsA = lds;                 // [32 rows][128 B]  (XOR-swizzled)
  char* ldsW = lds + 4096;          // [256 cols][128 B] (XOR-swizzled)
  float* red = (float*)(lds + 36864); // [2][32][8]
  int tid = threadIdx.x, w = tid >> 6, l = tid & 63;
  int r0 = blockIdx.x * 32;
  f32x16 acc;
#pragma unroll
  for (int i = 0; i < 16; ++i) acc[i] = 0.f;

  int lrow8 = l >> 3;
  int koffB = ((l & 7) ^ lrow8) * 8;   // pre-swizzled source k-offset (elements)
  int ra = l & 31, kb = (l >> 5) * 8;
  int colw = w * 32 + ra;

  for (int it = 0; it < 8; ++it) {
    int k0 = it * 64;
    __syncthreads();
    if (w < 4) {
      int row = 8 * w + lrow8;
      gload16(inpb + (size_t)(r0 + row) * KIN + k0 + koffB, ldsA + w * 1024);
    }
#pragma unroll
    for (int qi = 0; qi < 4; ++qi) {
      int q = 4 * w + qi;
      int c = 8 * q + lrow8;
      gload16(Wt + (size_t)c * KIN + k0 + koffB, ldsW + q * 1024);
    }
    __syncthreads();
    s16x8 av[4], bv[4];
#pragma unroll
    for (int kf = 0; kf < 4; ++kf) {
      int kk2 = (kf * 16 + kb) * 2;
      av[kf] = *(const s16x8*)(ldsA + ra * 128 + (kk2 ^ ((ra & 7) << 4)));
      bv[kf] = *(const s16x8*)(ldsW + colw * 128 + (kk2 ^ ((colw & 7) << 4)));
    }
#pragma unroll
    for (int kf = 0; kf < 4; ++kf) acc = mfma32(av[kf], bv[kf], acc);
  }

  float a1 = a_vec[colw], a2 = a_vec[256 + colw];
  int rquad = (l >> 5) * 4;
#pragma unroll
  for (int g = 0; g < 4; ++g) {
    int rowb = g * 8 + rquad;
    unsigned h0 = f2bf(acc[g * 4 + 0]), h1 = f2bf(acc[g * 4 + 1]);
    unsigned h2 = f2bf(acc[g * 4 + 2]), h3 = f2bf(acc[g * 4 + 3]);
    u32x2 pk;
    pk[0] = h0 | (h1 << 16);
    pk[1] = h2 | (h3 << 16);
    *(u32x2*)(Ht + (size_t)colw * N + r0 + rowb) = pk;
  }
#pragma unroll
  for (int g = 0; g < 16; ++g) {
    float vs = acc[g] * a1;
    float vn = acc[g] * a2;
#pragma unroll
    for (int m = 1; m <= 16; m <<= 1) {
      vs += __shfl_xor(vs, m, 64);
      vn += __shfl_xor(vn, m, 64);
    }
    if ((l & 31) == 0) {
      int row = (g & 3) + 8 * (g >> 2) + rquad;
      red[row * 8 + w] = vs;
      red[256 + row * 8 + w] = vn;
    }
  }
  __syncthreads();
  if (tid < 32) {
    float s = 0.f, n2 = 0.f;
#pragma unroll
    for (int i = 0; i < 8; ++i) { s += red[tid * 8 + i]; n2 += red[256 + tid * 8 + i]; }
    E[r0 + tid]   = expf(s);
    E5[r0 + tid]  = expf(0.2f * s);
    Fv[r0 + tid]  = expf(n2);
    F5v[r0 + tid] = expf(0.2f * n2);
  }
}

// ---------------- fused masked-softmax-numerator @ h: BARRIER-FREE --------------
// grid 512 = 256 row-blocks (32 rows) x KSPLIT=2 (j halves). 512 threads, 8 waves.
// Wave w owns feature cols 32w..32w+31 for ALL 32 rows. Each wave generates the
// P A-fragment IN REGISTERS (lane l: row=l&31, j=jt+(l>>5)*8+i — exactly the
// mfma_32x32x16 A layout) and loads the B-fragment (Ht[feat][j], 16B/lane)
// straight from L2-resident Ht. No LDS, no barriers: 8x redundant P-gen traded
// for pure-TLP latency hiding (2 blocks/CU, 16 indep waves). Rolling 2-set
// register prefetch; per-block tile-phase rotation de-syncs the adj HBM stream.
__global__ __launch_bounds__(512) void k_phase2(const int* __restrict__ adj,
                                                const unsigned short* __restrict__ Ht,
                                                const float* __restrict__ E,
                                                const float* __restrict__ E5,
                                                const float* __restrict__ Fv,
                                                const float* __restrict__ F5v,
                                                float* __restrict__ pacc,
                                                float* __restrict__ ps) {
  const int tid = threadIdx.x, w = tid >> 6, l = tid & 63;
  const int bid = blockIdx.x;
  const int rb = bid >> 1, ks = bid & 1;
  const int r0 = rb * 32;
  const int row = l & 31;
  const int kh = (l >> 5) * 8;            // j sub-offset within a 16-j tile
  const float Er = E[r0 + row], E5r = E5[r0 + row];
  const int start = (bid * 37) & 255;     // tile-phase rotation (256 tiles of 16 j)

  const int*            __restrict__ adjR = adj + (size_t)(r0 + row) * N + ks * 4096 + kh;
  const float*          __restrict__ FvR  = Fv  + ks * 4096 + kh;
  const float*          __restrict__ GvR  = F5v + ks * 4096 + kh;
  const unsigned short* __restrict__ HtR  = Ht + (size_t)(w * 32 + row) * N + ks * 4096 + kh;

  f32x16 acc;
#pragma unroll
  for (int i = 0; i < 16; ++i) acc[i] = 0.f;
  float s_part = 0.f;

  i32x4 adA0, adA1, adB0, adB1;
  f32x4 fA0, fA1, gA0, gA1, fB0, fB1, gB0, gB1;
  s16x8 bA, bB;

#define LOADSET(S, T)                                                          \
  { const int jo = ((start + (T)) & 255) * 16;                                 \
    ad##S##0 = *(const i32x4*)(adjR + jo);                                     \
    ad##S##1 = *(const i32x4*)(adjR + jo + 4);                                 \
    f##S##0  = *(const f32x4*)(FvR + jo);                                      \
    f##S##1  = *(const f32x4*)(FvR + jo + 4);                                  \
    g##S##0  = *(const f32x4*)(GvR + jo);                                      \
    g##S##1  = *(const f32x4*)(GvR + jo + 4);                                  \
    b##S     = *(const s16x8*)(HtR + jo); }

#define COMP(S)                                                                \
  { float p0 = (ad##S##0[0] != 0) ? fmaxf(Er * f##S##0[0], E5r * g##S##0[0]) : 0.f; \
    float p1 = (ad##S##0[1] != 0) ? fmaxf(Er * f##S##0[1], E5r * g##S##0[1]) : 0.f; \
    float p2 = (ad##S##0[2] != 0) ? fmaxf(Er * f##S##0[2], E5r * g##S##0[2]) : 0.f; \
    float p3 = (ad##S##0[3] != 0) ? fmaxf(Er * f##S##0[3], E5r * g##S##0[3]) : 0.f; \
    float p4 = (ad##S##1[0] != 0) ? fmaxf(Er * f##S##1[0], E5r * g##S##1[0]) : 0.f; \
    float p5 = (ad##S##1[1] != 0) ? fmaxf(Er * f##S##1[1], E5r * g##S##1[1]) : 0.f; \
    float p6 = (ad##S##1[2] != 0) ? fmaxf(Er * f##S##1[2], E5r * g##S##1[2]) : 0.f; \
    float p7 = (ad##S##1[3] != 0) ? fmaxf(Er * f##S##1[3], E5r * g##S##1[3]) : 0.f; \
    s_part += ((p0 + p1) + (p2 + p3)) + ((p4 + p5) + (p6 + p7));               \
    u32x4 pk;                                                                  \
    pk[0] = cvtpk(p0, p1); pk[1] = cvtpk(p2, p3);                              \
    pk[2] = cvtpk(p4, p5); pk[3] = cvtpk(p6, p7);                              \
    acc = mfma32(__builtin_bit_cast(s16x8, pk), b##S, acc); }

  LOADSET(A, 0)
  for (int t = 0; t < 256; t += 2) {
    LOADSET(B, t + 1)
    COMP(A)
    LOADSET(A, t + 2)   // t+2==256 wraps to tile `start`: harmless dead load
    COMP(B)
  }
#undef LOADSET
#undef COMP

  // ---- epilogue: rowsum (waves identical -> wave 0 writes), partial acc ----
  float s2 = s_part + __shfl_xor(s_part, 32, 64);
  if (w == 0 && l < 32) ps[(size_t)ks * N + r0 + l] = s2;

  float* po = pacc + (size_t)ks * N * F;
#pragma unroll
  for (int g = 0; g < 16; ++g) {
    int orow = (g & 3) + 8 * (g >> 2) + 4 * (l >> 5);
    po[(size_t)(r0 + orow) * F + w * 32 + row] = acc[g];
  }
}

// ---------------- combine split-K partials, normalize, ELU ----------------------
__global__ __launch_bounds__(256) void k_combine(const float* __restrict__ pacc,
                                                 const float* __restrict__ ps,
                                                 float* __restrict__ out) {
  int t = blockIdx.x * 256 + threadIdx.x;  // 524288 threads
  size_t idx = (size_t)t * 4;
  int row = (int)(idx >> 8);
  f32x4 a0 = *(const f32x4*)(pacc + idx);
  f32x4 a1 = *(const f32x4*)(pacc + (size_t)N * F + idx);
  float inv = 1.f / (ps[row] + ps[N + row]);
  f32x4 o;
#pragma unroll
  for (int i = 0; i < 4; ++i) {
    float v = (a0[i] + a1[i]) * inv;
    o[i] = v > 0.f ? v : expm1f(v);
  }
  *(f32x4*)(out + idx) = o;
}

extern "C" void kernel_launch(void* const* d_in, const int* in_sizes, int n_in,
                              void* d_out, int out_size, void* d_ws, size_t ws_size,
                              hipStream_t stream) {
  const float* input = (const float*)d_in[0];
  const int*   adj   = (const int*)d_in[1];
  const float* W     = (const float*)d_in[2];
  const float* a     = (const float*)d_in[3];
  float* out = (float*)d_out;
  char* ws = (char*)d_ws;

  unsigned short* inpb = (unsigned short*)(ws);              // 8,388,608 B
  unsigned short* Wt   = (unsigned short*)(ws + 8388608);    //   262,144 B
  unsigned short* Ht   = (unsigned short*)(ws + 8650752);    // 4,194,304 B
  float* E    = (float*)(ws + 12845056);                     //    32,768 B
  float* E5   = (float*)(ws + 12877824);
  float* Fv   = (float*)(ws + 12910592);
  float* F5   = (float*)(ws + 12943360);
  float* ps   = (float*)(ws + 12976128);                     //    65,536 B
  float* pacc = (float*)(ws + 13041664);                     // 16,777,216 B

  hipLaunchKernelGGL(k_cast,   dim3(2048), dim3(256), 0, stream, input, inpb, 524288);
  hipLaunchKernelGGL(k_prep_w, dim3(64),   dim3(256), 0, stream, W, Wt);
  hipLaunchKernelGGL(k_gemm1,  dim3(256),  dim3(512), 0, stream, inpb, Wt, a, Ht, E, E5, Fv, F5);
  hipLaunchKernelGGL(k_phase2, dim3(512),  dim3(512), 0, stream, adj, Ht, E, E5, Fv, F5, pacc, ps);
  hipLaunchKernelGGL(k_combine,dim3(2048), dim3(256), 0, stream, pacc, ps, out);
}

// Round 6
// 202.198 us; speedup vs baseline: 2.5718x; 2.5718x over previous
//
#include <hip/hip_runtime.h>
#include <hip/hip_bf16.h>
#include <math.h>

#define DEVI static __device__ __forceinline__

using f32x4  = __attribute__((ext_vector_type(4))) float;
using f32x16 = __attribute__((ext_vector_type(16))) float;
using s16x8  = __attribute__((ext_vector_type(8))) short;
using bf16x8 = __attribute__((ext_vector_type(8))) __bf16;
using u32x2  = __attribute__((ext_vector_type(2))) unsigned int;

constexpr int N   = 8192;
constexpr int KIN = 512;
constexpr int F   = 256;

DEVI unsigned f2bf(float f) {
  unsigned u = __builtin_bit_cast(unsigned, f);
  return ((u + 0x7FFFu + ((u >> 16) & 1u)) >> 16) & 0xFFFFu;
}

DEVI unsigned cvtpk(float lo, float hi) {
  unsigned r;
  asm("v_cvt_pk_bf16_f32 %0, %1, %2" : "=v"(r) : "v"(lo), "v"(hi));
  return r;
}

DEVI f32x16 mfma32(s16x8 a, s16x8 b, f32x16 c) {
  return __builtin_amdgcn_mfma_f32_32x32x16_bf16(
      __builtin_bit_cast(bf16x8, a), __builtin_bit_cast(bf16x8, b), c, 0, 0, 0);
}

DEVI void gload16(const void* g, void* lds_uniform) {
  __builtin_amdgcn_global_load_lds(
      (const __attribute__((address_space(1))) unsigned*)g,
      (__attribute__((address_space(3))) unsigned*)lds_uniform, 16, 0, 0);
}

// ---------------- pack adj int32 [8192][8192] -> bitmask [8192][1024 B] ---------
// bit (j&7) of byte mask[i*1024 + (j>>3)] = (adj[i][j] != 0). Pure coalesced
// stream: wave-chunk = 256 ints; 4x dword load (64 lanes x 4B contiguous),
// 4x ballot, lanes 0-3 store one u64 each (32B contiguous). 2048 blocks x 256.
__global__ __launch_bounds__(256) void k_pack(const int* __restrict__ adj,
                                              unsigned long long* __restrict__ mask) {
  const int wid = (blockIdx.x << 2) | ((int)threadIdx.x >> 6);   // 0..8191
  const int l = threadIdx.x & 63;
#pragma unroll 1
  for (int s = 0; s < 32; ++s) {
    const size_t base = ((size_t)(s * 8192 + wid)) << 8;
    int v0 = adj[base + l];
    int v1 = adj[base + 64 + l];
    int v2 = adj[base + 128 + l];
    int v3 = adj[base + 192 + l];
    unsigned long long b0 = __ballot(v0 != 0);
    unsigned long long b1 = __ballot(v1 != 0);
    unsigned long long b2 = __ballot(v2 != 0);
    unsigned long long b3 = __ballot(v3 != 0);
    if (l < 4) {
      unsigned long long b = (l == 0) ? b0 : (l == 1) ? b1 : (l == 2) ? b2 : b3;
      mask[(base >> 6) + l] = b;
    }
  }
}

// ---------------- cast input f32 -> bf16 (row-major [8192][512]) ----------------
__global__ __launch_bounds__(256) void k_cast(const float* __restrict__ src,
                                              unsigned short* __restrict__ dst,
                                              int n8) {
  int t = blockIdx.x * 256 + threadIdx.x;
  if (t >= n8) return;
  const f32x4* p = (const f32x4*)(src + (size_t)t * 8);
  f32x4 v0 = p[0], v1 = p[1];
  s16x8 o;
  o[0] = (short)f2bf(v0[0]); o[1] = (short)f2bf(v0[1]);
  o[2] = (short)f2bf(v0[2]); o[3] = (short)f2bf(v0[3]);
  o[4] = (short)f2bf(v1[0]); o[5] = (short)f2bf(v1[1]);
  o[6] = (short)f2bf(v1[2]); o[7] = (short)f2bf(v1[3]);
  *(s16x8*)(dst + (size_t)t * 8) = o;
}

// ---------------- W [512][256] f32 -> Wt [256][512] bf16 (transposed) -----------
__global__ __launch_bounds__(256) void k_prep_w(const float* __restrict__ W,
                                                unsigned short* __restrict__ Wt) {
  int t = blockIdx.x * 256 + threadIdx.x;   // 16384 threads
  int c = t >> 6, k0 = (t & 63) * 8;
  s16x8 o;
#pragma unroll
  for (int i = 0; i < 8; ++i) o[i] = (short)f2bf(W[(size_t)(k0 + i) * F + c]);
  *(s16x8*)(Wt + (size_t)c * KIN + k0) = o;
}

// ---------------- h = Xbf @ Wt^T : writes Ht[256][8192] bf16 + E/E5/F/F5 --------
__global__ __launch_bounds__(512) void k_gemm1(const unsigned short* __restrict__ inpb,
                                               const unsigned short* __restrict__ Wt,
                                               const float* __restrict__ a_vec,
                                               unsigned short* __restrict__ Ht,
                                               float* __restrict__ E, float* __restrict__ E5,
                                               float* __restrict__ Fv, float* __restrict__ F5v) {
  __shared__ __align__(16) char lds[4096 + 32768 + 2048];
  char* ldsA = lds;                 // [32 rows][128 B]  (XOR-swizzled)
  char* ldsW = lds + 4096;          // [256 cols][128 B] (XOR-swizzled)
  float* red = (float*)(lds + 36864); // [2][32][8]
  int tid = threadIdx.x, w = tid >> 6, l = tid & 63;
  int r0 = blockIdx.x * 32;
  f32x16 acc;
#pragma unroll
  for (int i = 0; i < 16; ++i) acc[i] = 0.f;

  int lrow8 = l >> 3;
  int koffB = ((l & 7) ^ lrow8) * 8;   // pre-swizzled source k-offset (elements)
  int ra = l & 31, kb = (l >> 5) * 8;
  int colw = w * 32 + ra;

  for (int it = 0; it < 8; ++it) {
    int k0 = it * 64;
    __syncthreads();
    if (w < 4) {
      int row = 8 * w + lrow8;
      gload16(inpb + (size_t)(r0 + row) * KIN + k0 + koffB, ldsA + w * 1024);
    }
#pragma unroll
    for (int qi = 0; qi < 4; ++qi) {
      int q = 4 * w + qi;
      int c = 8 * q + lrow8;
      gload16(Wt + (size_t)c * KIN + k0 + koffB, ldsW + q * 1024);
    }
    __syncthreads();
    s16x8 av[4], bv[4];
#pragma unroll
    for (int kf = 0; kf < 4; ++kf) {
      int kk2 = (kf * 16 + kb) * 2;
      av[kf] = *(const s16x8*)(ldsA + ra * 128 + (kk2 ^ ((ra & 7) << 4)));
      bv[kf] = *(const s16x8*)(ldsW + colw * 128 + (kk2 ^ ((colw & 7) << 4)));
    }
#pragma unroll
    for (int kf = 0; kf < 4; ++kf) acc = mfma32(av[kf], bv[kf], acc);
  }

  float a1 = a_vec[colw], a2 = a_vec[256 + colw];
  int rquad = (l >> 5) * 4;
#pragma unroll
  for (int g = 0; g < 4; ++g) {
    int rowb = g * 8 + rquad;
    unsigned h0 = f2bf(acc[g * 4 + 0]), h1 = f2bf(acc[g * 4 + 1]);
    unsigned h2 = f2bf(acc[g * 4 + 2]), h3 = f2bf(acc[g * 4 + 3]);
    u32x2 pk;
    pk[0] = h0 | (h1 << 16);
    pk[1] = h2 | (h3 << 16);
    *(u32x2*)(Ht + (size_t)colw * N + r0 + rowb) = pk;
  }
#pragma unroll
  for (int g = 0; g < 16; ++g) {
    float vs = acc[g] * a1;
    float vn = acc[g] * a2;
#pragma unroll
    for (int m = 1; m <= 16; m <<= 1) {
      vs += __shfl_xor(vs, m, 64);
      vn += __shfl_xor(vn, m, 64);
    }
    if ((l & 31) == 0) {
      int row = (g & 3) + 8 * (g >> 2) + rquad;
      red[row * 8 + w] = vs;
      red[256 + row * 8 + w] = vn;
    }
  }
  __syncthreads();
  if (tid < 32) {
    float s = 0.f, n2 = 0.f;
#pragma unroll
    for (int i = 0; i < 8; ++i) { s += red[tid * 8 + i]; n2 += red[256 + tid * 8 + i]; }
    E[r0 + tid]   = expf(s);
    E5[r0 + tid]  = expf(0.2f * s);
    Fv[r0 + tid]  = expf(n2);
    F5v[r0 + tid] = expf(0.2f * n2);
  }
}

// ---------------- fused masked-softmax @ h, bitmask-fed, fused epilogue ---------
// 256 blocks x 32 rows, 512 threads, 8 waves (wave w = feature cols 32w..+31).
// Full j sweep: 128 iters of 64 j. All loop inputs are small/L2-resident:
// mask byte (1) + F (1) + F5 (1) reg-prefetched depth 1; Ht staged to LDS via
// global_load_lds double-buffer (L2-resident source). One barrier per iter;
// counted vmcnt(3) leaves only next-iter pf in flight. Epilogue: rowsum ->
// normalize -> ELU -> store (no split-K, no combine kernel).
__global__ __launch_bounds__(512) void k_phase2(const unsigned char* __restrict__ maskB,
                                                const unsigned short* __restrict__ Ht,
                                                const float* __restrict__ E,
                                                const float* __restrict__ E5,
                                                const float* __restrict__ Fv,
                                                const float* __restrict__ F5v,
                                                float* __restrict__ out) {
  __shared__ __align__(16) char lds[65536 + 8192 + 128];
  char* ldsH = lds;                        // 2 x [256 feat][64 j] bf16, swizzled
  char* ldsP = lds + 65536;                // 2 x [32 rows][64 j] bf16, swizzled
  float* ldsS = (float*)(lds + 65536 + 8192); // [32] 1/rowsum

  const int tid = threadIdx.x, w = tid >> 6, l = tid & 63;
  const int r0 = blockIdx.x * 32;

  // producer role: thread covers row r, j = it*64 + cch*4 .. +3
  const int r = tid >> 4;
  const int cch = tid & 15;
  const float Er = E[r0 + r], E5r = E5[r0 + r];
  float s_part = 0.f;
  const unsigned char* mrow = maskB + (size_t)(r0 + r) * 1024;
  const int mshift = (cch & 1) * 4;
  const int pw_byte = r * 128 + ((cch * 8) ^ ((r & 7) << 4));

  // staging / consumer addressing
  const int lrow8 = l >> 3;
  const int koffB = ((l & 7) ^ lrow8) * 8;   // pre-swizzled source offset (elems)
  const int ra = l & 31;
  const int kb = (l >> 5) * 8;
  const int colw = w * 32 + (l & 31);

  f32x16 acc;
#pragma unroll
  for (int i = 0; i < 16; ++i) acc[i] = 0.f;

  // ---- prologue: pf(it=0) [3 VMEM] + stage H(0) into buf 0 [4 VMEM] ----
  unsigned mcur = mrow[cch >> 1];
  f32x4 fcur = *(const f32x4*)(Fv + cch * 4);
  f32x4 gcur = *(const f32x4*)(F5v + cch * 4);
#pragma unroll
  for (int qi = 0; qi < 4; ++qi) {
    int q = 4 * w + qi;
    int c = 8 * q + lrow8;
    gload16(Ht + (size_t)c * N + koffB, ldsH + q * 1024);
  }

  for (int it = 0; it < 128; ++it) {
    const int cur = it & 1;
    char* Hc = ldsH + cur * 32768;
    char* Hn = ldsH + (cur ^ 1) * 32768;
    char* Pc = ldsP + cur * 4096;
    const int itn = (it + 1) & 127;
    const int jn = itn * 64;

    // pf next iter (3 VMEM loads)
    unsigned mn = mrow[itn * 8 + (cch >> 1)];
    f32x4 fn = *(const f32x4*)(Fv + jn + cch * 4);
    f32x4 gn = *(const f32x4*)(F5v + jn + cch * 4);

    // P-gen(it) from current regs (compiler auto-waits on pf(it))
    {
      unsigned mb = mcur >> mshift;
      float p0 = (mb & 1u) ? fmaxf(Er * fcur[0], E5r * gcur[0]) : 0.f;
      float p1 = (mb & 2u) ? fmaxf(Er * fcur[1], E5r * gcur[1]) : 0.f;
      float p2 = (mb & 4u) ? fmaxf(Er * fcur[2], E5r * gcur[2]) : 0.f;
      float p3 = (mb & 8u) ? fmaxf(Er * fcur[3], E5r * gcur[3]) : 0.f;
      s_part += (p0 + p1) + (p2 + p3);
      u32x2 pk;
      pk[0] = cvtpk(p0, p1);
      pk[1] = cvtpk(p2, p3);
      *(u32x2*)(Pc + pw_byte) = pk;
    }

    // retire stage(it) [issued last iter]; leave only pf(next)=3 in flight
    asm volatile("s_waitcnt vmcnt(3) lgkmcnt(0)" ::: "memory");
    __builtin_amdgcn_s_barrier();

    // fragment reads from current buffers
    s16x8 av[4], bv[4];
#pragma unroll
    for (int kf = 0; kf < 4; ++kf) {
      int kk2 = (kf * 16 + kb) * 2;
      av[kf] = *(const s16x8*)(Pc + ra * 128 + (kk2 ^ ((ra & 7) << 4)));
      bv[kf] = *(const s16x8*)(Hc + colw * 128 + (kk2 ^ ((colw & 7) << 4)));
    }
    asm volatile("s_waitcnt lgkmcnt(0)" ::: "memory");
    __builtin_amdgcn_sched_barrier(0);

    // stage H(it+1) into Hn (safe post-barrier: all prior reads of Hn drained)
#pragma unroll
    for (int qi = 0; qi < 4; ++qi) {
      int q = 4 * w + qi;
      int c = 8 * q + lrow8;
      gload16(Ht + (size_t)c * N + jn + koffB, Hn + q * 1024);
    }

    acc = mfma32(av[0], bv[0], acc);
    acc = mfma32(av[1], bv[1], acc);
    acc = mfma32(av[2], bv[2], acc);
    acc = mfma32(av[3], bv[3], acc);

    mcur = mn; fcur = fn; gcur = gn;
  }

  // ---- epilogue: rowsum -> 1/s, normalize, ELU, store ----
  __syncthreads();   // full drain (incl. wrapped dead stage)
  float s = s_part;
#pragma unroll
  for (int m = 1; m <= 8; m <<= 1) s += __shfl_xor(s, m, 64);
  if ((tid & 15) == 0) ldsS[r] = 1.f / s;
  __syncthreads();
#pragma unroll
  for (int g = 0; g < 16; ++g) {
    int row = (g & 3) + 8 * (g >> 2) + 4 * (l >> 5);
    float v = acc[g] * ldsS[row];
    out[(size_t)(r0 + row) * F + colw] = v > 0.f ? v : expm1f(v);
  }
}

extern "C" void kernel_launch(void* const* d_in, const int* in_sizes, int n_in,
                              void* d_out, int out_size, void* d_ws, size_t ws_size,
                              hipStream_t stream) {
  const float* input = (const float*)d_in[0];
  const int*   adj   = (const int*)d_in[1];
  const float* W     = (const float*)d_in[2];
  const float* a     = (const float*)d_in[3];
  float* out = (float*)d_out;
  char* ws = (char*)d_ws;

  unsigned short* inpb = (unsigned short*)(ws);              // 8,388,608 B
  unsigned short* Wt   = (unsigned short*)(ws + 8388608);    //   262,144 B
  unsigned short* Ht   = (unsigned short*)(ws + 8650752);    // 4,194,304 B
  float* E    = (float*)(ws + 12845056);                     //    32,768 B
  float* E5   = (float*)(ws + 12877824);
  float* Fv   = (float*)(ws + 12910592);
  float* F5   = (float*)(ws + 12943360);
  unsigned long long* mask = (unsigned long long*)(ws + 13041664); // 8,388,608 B

  hipLaunchKernelGGL(k_pack,   dim3(2048), dim3(256), 0, stream, adj, mask);
  hipLaunchKernelGGL(k_cast,   dim3(2048), dim3(256), 0, stream, input, inpb, 524288);
  hipLaunchKernelGGL(k_prep_w, dim3(64),   dim3(256), 0, stream, W, Wt);
  hipLaunchKernelGGL(k_gemm1,  dim3(256),  dim3(512), 0, stream, inpb, Wt, a, Ht, E, E5, Fv, F5);
  hipLaunchKernelGGL(k_phase2, dim3(256),  dim3(512), 0, stream,
                     (const unsigned char*)mask, Ht, E, E5, Fv, F5, out);
}

// Round 7
// 154.935 us; speedup vs baseline: 3.3564x; 1.3051x over previous
//
#include <hip/hip_runtime.h>
#include <hip/hip_bf16.h>
#include <math.h>

#define DEVI static __device__ __forceinline__

using f32x4  = __attribute__((ext_vector_type(4))) float;
using f32x16 = __attribute__((ext_vector_type(16))) float;
using s16x8  = __attribute__((ext_vector_type(8))) short;
using bf16x8 = __attribute__((ext_vector_type(8))) __bf16;
using i32x4  = __attribute__((ext_vector_type(4))) int;
using u32x2  = __attribute__((ext_vector_type(2))) unsigned int;
using u32x4  = __attribute__((ext_vector_type(4))) unsigned int;

constexpr int N   = 8192;
constexpr int KIN = 512;
constexpr int F   = 256;

DEVI unsigned f2bf(float f) {
  unsigned u = __builtin_bit_cast(unsigned, f);
  return ((u + 0x7FFFu + ((u >> 16) & 1u)) >> 16) & 0xFFFFu;
}

DEVI unsigned cvtpk(float lo, float hi) {
  unsigned r;
  asm("v_cvt_pk_bf16_f32 %0, %1, %2" : "=v"(r) : "v"(lo), "v"(hi));
  return r;
}

DEVI f32x16 mfma32(s16x8 a, s16x8 b, f32x16 c) {
  return __builtin_amdgcn_mfma_f32_32x32x16_bf16(
      __builtin_bit_cast(bf16x8, a), __builtin_bit_cast(bf16x8, b), c, 0, 0, 0);
}

DEVI void gload16(const void* g, void* lds_uniform) {
  __builtin_amdgcn_global_load_lds(
      (const __attribute__((address_space(1))) unsigned*)g,
      (__attribute__((address_space(3))) unsigned*)lds_uniform, 16, 0, 0);
}

// ---------------- cast input f32 -> bf16 (row-major [8192][512]) ----------------
__global__ __launch_bounds__(256) void k_cast(const float* __restrict__ src,
                                              unsigned short* __restrict__ dst,
                                              int n8) {
  int t = blockIdx.x * 256 + threadIdx.x;
  if (t >= n8) return;
  const f32x4* p = (const f32x4*)(src + (size_t)t * 8);
  f32x4 v0 = p[0], v1 = p[1];
  s16x8 o;
  o[0] = (short)f2bf(v0[0]); o[1] = (short)f2bf(v0[1]);
  o[2] = (short)f2bf(v0[2]); o[3] = (short)f2bf(v0[3]);
  o[4] = (short)f2bf(v1[0]); o[5] = (short)f2bf(v1[1]);
  o[6] = (short)f2bf(v1[2]); o[7] = (short)f2bf(v1[3]);
  *(s16x8*)(dst + (size_t)t * 8) = o;
}

// ---------------- W [512][256] f32 -> Wt [256][512] bf16 (transposed) -----------
__global__ __launch_bounds__(256) void k_prep_w(const float* __restrict__ W,
                                                unsigned short* __restrict__ Wt) {
  int t = blockIdx.x * 256 + threadIdx.x;   // 16384 threads
  int c = t >> 6, k0 = (t & 63) * 8;
  s16x8 o;
#pragma unroll
  for (int i = 0; i < 8; ++i) o[i] = (short)f2bf(W[(size_t)(k0 + i) * F + c]);
  *(s16x8*)(Wt + (size_t)c * KIN + k0) = o;
}

// ---------------- h = Xbf @ Wt^T : writes Hj + E/E5/F/F5 ------------------------
// Hj layout: [512 j-groups][256 feats][16 j] bf16 (4 MB) so phase2 B-frag loads
// (wave = 32 consecutive feats x 16 j) are 1KB contiguous.
__global__ __launch_bounds__(512) void k_gemm1(const unsigned short* __restrict__ inpb,
                                               const unsigned short* __restrict__ Wt,
                                               const float* __restrict__ a_vec,
                                               unsigned short* __restrict__ Hj,
                                               float* __restrict__ E, float* __restrict__ E5,
                                               float* __restrict__ Fv, float* __restrict__ F5v) {
  __shared__ __align__(16) char lds[4096 + 32768 + 2048];
  char* ldsA = lds;                 // [32 rows][128 B]  (XOR-swizzled)
  char* ldsW = lds + 4096;          // [256 cols][128 B] (XOR-swizzled)
  float* red = (float*)(lds + 36864); // [2][32][8]
  int tid = threadIdx.x, w = tid >> 6, l = tid & 63;
  int r0 = blockIdx.x * 32;
  f32x16 acc;
#pragma unroll
  for (int i = 0; i < 16; ++i) acc[i] = 0.f;

  int lrow8 = l >> 3;
  int koffB = ((l & 7) ^ lrow8) * 8;   // pre-swizzled source k-offset (elements)
  int ra = l & 31, kb = (l >> 5) * 8;
  int colw = w * 32 + ra;

  for (int it = 0; it < 8; ++it) {
    int k0 = it * 64;
    __syncthreads();
    if (w < 4) {
      int row = 8 * w + lrow8;
      gload16(inpb + (size_t)(r0 + row) * KIN + k0 + koffB, ldsA + w * 1024);
    }
#pragma unroll
    for (int qi = 0; qi < 4; ++qi) {
      int q = 4 * w + qi;
      int c = 8 * q + lrow8;
      gload16(Wt + (size_t)c * KIN + k0 + koffB, ldsW + q * 1024);
    }
    __syncthreads();
    s16x8 av[4], bv[4];
#pragma unroll
    for (int kf = 0; kf < 4; ++kf) {
      int kk2 = (kf * 16 + kb) * 2;
      av[kf] = *(const s16x8*)(ldsA + ra * 128 + (kk2 ^ ((ra & 7) << 4)));
      bv[kf] = *(const s16x8*)(ldsW + colw * 128 + (kk2 ^ ((colw & 7) << 4)));
    }
#pragma unroll
    for (int kf = 0; kf < 4; ++kf) acc = mfma32(av[kf], bv[kf], acc);
  }

  float a1 = a_vec[colw], a2 = a_vec[256 + colw];
  int rquad = (l >> 5) * 4;
#pragma unroll
  for (int g = 0; g < 4; ++g) {
    int jj = r0 + g * 8 + rquad;        // 4-aligned, same 16-group for jj..jj+3
    unsigned h0 = f2bf(acc[g * 4 + 0]), h1 = f2bf(acc[g * 4 + 1]);
    unsigned h2 = f2bf(acc[g * 4 + 2]), h3 = f2bf(acc[g * 4 + 3]);
    u32x2 pk;
    pk[0] = h0 | (h1 << 16);
    pk[1] = h2 | (h3 << 16);
    *(u32x2*)(Hj + ((size_t)(jj >> 4)) * 4096 + colw * 16 + (jj & 15)) = pk;
  }
#pragma unroll
  for (int g = 0; g < 16; ++g) {
    float vs = acc[g] * a1;
    float vn = acc[g] * a2;
#pragma unroll
    for (int m = 1; m <= 16; m <<= 1) {
      vs += __shfl_xor(vs, m, 64);
      vn += __shfl_xor(vn, m, 64);
    }
    if ((l & 31) == 0) {
      int row = (g & 3) + 8 * (g >> 2) + rquad;
      red[row * 8 + w] = vs;
      red[256 + row * 8 + w] = vn;
    }
  }
  __syncthreads();
  if (tid < 32) {
    float s = 0.f, n2 = 0.f;
#pragma unroll
    for (int i = 0; i < 8; ++i) { s += red[tid * 8 + i]; n2 += red[256 + tid * 8 + i]; }
    E[r0 + tid]   = expf(s);
    E5[r0 + tid]  = expf(0.2f * s);
    Fv[r0 + tid]  = expf(n2);
    F5v[r0 + tid] = expf(0.2f * n2);
  }
}

// ---------------- fused masked-softmax @ h: barrier-free dataflow ----------------
// 256 blocks x 32 rows, 512 threads, 8 waves. Wave w owns j in [w*1024,(w+1)*1024)
// for ALL 256 feats (acc = 8 x f32x16). Per 16-j tile per wave:
//  - adj: 2 per-lane i32x4 loads (row = l&31, j-slice kh=(l>>5)*8). Lanes l,l+32
//    share a row => each 64B adj line fully consumed by the instr pair. adj read
//    ONCE chip-wide, coalesced-by-line: no pack kernel.
//  - F/G: broadcast f32x4 loads (2 distinct addrs/instr).
//  - P A-frag built in regs (R5-proven bit-exact): max(Er*F, E5r*G) masked.
//  - B-frags: 8 coalesced 1KB s16x8 loads from Hj (L2-resident).
// No LDS, no barriers in the loop; depth-2 rolling prefetch (2 named sets,
// unroll-2, all-static indexing). End: cross-wave acc+rowsum reduce via LDS,
// normalize, ELU, store.
__global__ __launch_bounds__(512) void k_phase2(const int* __restrict__ adj,
                                                const unsigned short* __restrict__ Hj,
                                                const float* __restrict__ E,
                                                const float* __restrict__ E5,
                                                const float* __restrict__ Fv,
                                                const float* __restrict__ F5v,
                                                float* __restrict__ out) {
  __shared__ __align__(16) float ldsRed[8][1024];   // 32 KB
  __shared__ float ldsS[8][32];
  __shared__ float ldsInv[32];

  const int tid = threadIdx.x, w = tid >> 6, l = tid & 63;
  const int r0 = blockIdx.x * 32;
  const int row = l & 31;
  const int kh = (l >> 5) * 8;
  const float Er = E[r0 + row], E5r = E5[r0 + row];

  const int jbase = w * 1024;
  const int*            __restrict__ adjR = adj + (size_t)(r0 + row) * N + jbase + kh;
  const float*          __restrict__ FvR  = Fv  + jbase + kh;
  const float*          __restrict__ GvR  = F5v + jbase + kh;
  // Hj base for this wave: group = w*64 + t ; within group: feat*16 + j%16
  const unsigned short* __restrict__ HjR  = Hj + ((size_t)(w * 64)) * 4096 + row * 16 + kh;

  f32x16 acc[8];
#pragma unroll
  for (int fg = 0; fg < 8; ++fg)
#pragma unroll
    for (int i = 0; i < 16; ++i) acc[fg][i] = 0.f;
  float s_part = 0.f;

  i32x4 adA0, adA1, adB0, adB1;
  f32x4 fA0, fA1, gA0, gA1, fB0, fB1, gB0, gB1;

#define LOADSET(S, T)                                                          \
  { const int jo = (T) * 16;                                                   \
    ad##S##0 = *(const i32x4*)(adjR + jo);                                     \
    ad##S##1 = *(const i32x4*)(adjR + jo + 4);                                 \
    f##S##0  = *(const f32x4*)(FvR + jo);                                      \
    f##S##1  = *(const f32x4*)(FvR + jo + 4);                                  \
    g##S##0  = *(const f32x4*)(GvR + jo);                                      \
    g##S##1  = *(const f32x4*)(GvR + jo + 4); }

#define TILE(S, T)                                                             \
  { const int t = (T);                                                         \
    const unsigned short* hb = HjR + (size_t)t * 4096;                         \
    /* P-gen from set S (loaded 2 tiles ago) */                                \
    float p0 = (ad##S##0[0] != 0) ? fmaxf(Er * f##S##0[0], E5r * g##S##0[0]) : 0.f; \
    float p1 = (ad##S##0[1] != 0) ? fmaxf(Er * f##S##0[1], E5r * g##S##0[1]) : 0.f; \
    float p2 = (ad##S##0[2] != 0) ? fmaxf(Er * f##S##0[2], E5r * g##S##0[2]) : 0.f; \
    float p3 = (ad##S##0[3] != 0) ? fmaxf(Er * f##S##0[3], E5r * g##S##0[3]) : 0.f; \
    float p4 = (ad##S##1[0] != 0) ? fmaxf(Er * f##S##1[0], E5r * g##S##1[0]) : 0.f; \
    float p5 = (ad##S##1[1] != 0) ? fmaxf(Er * f##S##1[1], E5r * g##S##1[1]) : 0.f; \
    float p6 = (ad##S##1[2] != 0) ? fmaxf(Er * f##S##1[2], E5r * g##S##1[2]) : 0.f; \
    float p7 = (ad##S##1[3] != 0) ? fmaxf(Er * f##S##1[3], E5r * g##S##1[3]) : 0.f; \
    s_part += ((p0 + p1) + (p2 + p3)) + ((p4 + p5) + (p6 + p7));               \
    u32x4 pk;                                                                  \
    pk[0] = cvtpk(p0, p1); pk[1] = cvtpk(p2, p3);                              \
    pk[2] = cvtpk(p4, p5); pk[3] = cvtpk(p6, p7);                              \
    const s16x8 aF = __builtin_bit_cast(s16x8, pk);                            \
    /* reload set S for tile t+2 (wraps harmlessly at the tail) */             \
    LOADSET(S, (t + 2) & 63)                                                   \
    _Pragma("unroll")                                                          \
    for (int fg = 0; fg < 8; ++fg) {                                           \
      s16x8 b = *(const s16x8*)(hb + fg * 512);                                \
      acc[fg] = mfma32(aF, b, acc[fg]);                                        \
    }                                                                          \
  }

  LOADSET(A, 0)
  LOADSET(B, 1)
  for (int ito = 0; ito < 32; ++ito) {
    TILE(A, ito * 2)
    TILE(B, ito * 2 + 1)
  }
#undef TILE
#undef LOADSET

  // ---- epilogue: rowsum across kh-halves + waves, then acc reduce + ELU ----
  float s2 = s_part + __shfl_xor(s_part, 32, 64);
  if (l < 32) ldsS[w][l] = s2;
  __syncthreads();
  if (tid < 32) {
    float s = 0.f;
#pragma unroll
    for (int i = 0; i < 8; ++i) s += ldsS[i][tid];
    ldsInv[tid] = 1.f / s;
  }
  __syncthreads();
#pragma unroll
  for (int sfg = 0; sfg < 8; ++sfg) {
#pragma unroll
    for (int i4 = 0; i4 < 4; ++i4) {
      f32x4 v;
#pragma unroll
      for (int i = 0; i < 4; ++i) v[i] = acc[sfg][i4 * 4 + i];
      *(f32x4*)(&ldsRed[w][l * 16 + i4 * 4]) = v;
    }
    __syncthreads();
#pragma unroll
    for (int e2 = 0; e2 < 2; ++e2) {
      int e = tid * 2 + e2;
      float v = 0.f;
#pragma unroll
      for (int i = 0; i < 8; ++i) v += ldsRed[i][e];
      int le = e >> 4, ii = e & 15;
      int orow = (ii & 3) + 8 * (ii >> 2) + 4 * (le >> 5);
      int feat = sfg * 32 + (le & 31);
      float x = v * ldsInv[orow];
      out[(size_t)(r0 + orow) * F + feat] = x > 0.f ? x : expm1f(x);
    }
    __syncthreads();
  }
}

extern "C" void kernel_launch(void* const* d_in, const int* in_sizes, int n_in,
                              void* d_out, int out_size, void* d_ws, size_t ws_size,
                              hipStream_t stream) {
  const float* input = (const float*)d_in[0];
  const int*   adj   = (const int*)d_in[1];
  const float* W     = (const float*)d_in[2];
  const float* a     = (const float*)d_in[3];
  float* out = (float*)d_out;
  char* ws = (char*)d_ws;

  unsigned short* inpb = (unsigned short*)(ws);              // 8,388,608 B
  unsigned short* Wt   = (unsigned short*)(ws + 8388608);    //   262,144 B
  unsigned short* Hj   = (unsigned short*)(ws + 8650752);    // 4,194,304 B
  float* E    = (float*)(ws + 12845056);                     //    32,768 B
  float* E5   = (float*)(ws + 12877824);
  float* Fv   = (float*)(ws + 12910592);
  float* F5   = (float*)(ws + 12943360);

  hipLaunchKernelGGL(k_cast,   dim3(2048), dim3(256), 0, stream, input, inpb, 524288);
  hipLaunchKernelGGL(k_prep_w, dim3(64),   dim3(256), 0, stream, W, Wt);
  hipLaunchKernelGGL(k_gemm1,  dim3(256),  dim3(512), 0, stream, inpb, Wt, a, Hj, E, E5, Fv, F5);
  hipLaunchKernelGGL(k_phase2, dim3(256),  dim3(512), 0, stream, adj, Hj, E, E5, Fv, F5, out);
}

// Round 8
// 144.183 us; speedup vs baseline: 3.6066x; 1.0746x over previous
//
#include <hip/hip_runtime.h>
#include <hip/hip_bf16.h>
#include <math.h>

#define DEVI static __device__ __forceinline__

using f32x4  = __attribute__((ext_vector_type(4))) float;
using f32x16 = __attribute__((ext_vector_type(16))) float;
using s16x8  = __attribute__((ext_vector_type(8))) short;
using bf16x8 = __attribute__((ext_vector_type(8))) __bf16;
using i32x4  = __attribute__((ext_vector_type(4))) int;
using u32x2  = __attribute__((ext_vector_type(2))) unsigned int;
using u32x4  = __attribute__((ext_vector_type(4))) unsigned int;

constexpr int N   = 8192;
constexpr int KIN = 512;
constexpr int F   = 256;

DEVI unsigned f2bf(float f) {
  unsigned u = __builtin_bit_cast(unsigned, f);
  return ((u + 0x7FFFu + ((u >> 16) & 1u)) >> 16) & 0xFFFFu;
}

DEVI unsigned cvtpk(float lo, float hi) {
  unsigned r;
  asm("v_cvt_pk_bf16_f32 %0, %1, %2" : "=v"(r) : "v"(lo), "v"(hi));
  return r;
}

DEVI f32x16 mfma32(s16x8 a, s16x8 b, f32x16 c) {
  return __builtin_amdgcn_mfma_f32_32x32x16_bf16(
      __builtin_bit_cast(bf16x8, a), __builtin_bit_cast(bf16x8, b), c, 0, 0, 0);
}

DEVI void gload16(const void* g, void* lds_uniform) {
  __builtin_amdgcn_global_load_lds(
      (const __attribute__((address_space(1))) unsigned*)g,
      (__attribute__((address_space(3))) unsigned*)lds_uniform, 16, 0, 0);
}

// ---------------- cast input f32 -> bf16 (row-major [8192][512]) ----------------
__global__ __launch_bounds__(256) void k_cast(const float* __restrict__ src,
                                              unsigned short* __restrict__ dst,
                                              int n8) {
  int t = blockIdx.x * 256 + threadIdx.x;
  if (t >= n8) return;
  const f32x4* p = (const f32x4*)(src + (size_t)t * 8);
  f32x4 v0 = p[0], v1 = p[1];
  s16x8 o;
  o[0] = (short)f2bf(v0[0]); o[1] = (short)f2bf(v0[1]);
  o[2] = (short)f2bf(v0[2]); o[3] = (short)f2bf(v0[3]);
  o[4] = (short)f2bf(v1[0]); o[5] = (short)f2bf(v1[1]);
  o[6] = (short)f2bf(v1[2]); o[7] = (short)f2bf(v1[3]);
  *(s16x8*)(dst + (size_t)t * 8) = o;
}

// ---------------- W [512][256] f32 -> Wt [256][512] bf16 (transposed) -----------
__global__ __launch_bounds__(256) void k_prep_w(const float* __restrict__ W,
                                                unsigned short* __restrict__ Wt) {
  int t = blockIdx.x * 256 + threadIdx.x;   // 16384 threads
  int c = t >> 6, k0 = (t & 63) * 8;
  s16x8 o;
#pragma unroll
  for (int i = 0; i < 8; ++i) o[i] = (short)f2bf(W[(size_t)(k0 + i) * F + c]);
  *(s16x8*)(Wt + (size_t)c * KIN + k0) = o;
}

// ---------------- h = Xbf @ Wt^T : writes Hj + E/E5/F/F5 ------------------------
// Hj layout: [512 j-groups][256 feats][16 j] bf16 (4 MB) so phase2 B-frag loads
// (wave = 32 consecutive feats x 16 j) are 1KB contiguous.
__global__ __launch_bounds__(512) void k_gemm1(const unsigned short* __restrict__ inpb,
                                               const unsigned short* __restrict__ Wt,
                                               const float* __restrict__ a_vec,
                                               unsigned short* __restrict__ Hj,
                                               float* __restrict__ E, float* __restrict__ E5,
                                               float* __restrict__ Fv, float* __restrict__ F5v) {
  __shared__ __align__(16) char lds[4096 + 32768 + 2048];
  char* ldsA = lds;                 // [32 rows][128 B]  (XOR-swizzled)
  char* ldsW = lds + 4096;          // [256 cols][128 B] (XOR-swizzled)
  float* red = (float*)(lds + 36864); // [2][32][8]
  int tid = threadIdx.x, w = tid >> 6, l = tid & 63;
  int r0 = blockIdx.x * 32;
  f32x16 acc;
#pragma unroll
  for (int i = 0; i < 16; ++i) acc[i] = 0.f;

  int lrow8 = l >> 3;
  int koffB = ((l & 7) ^ lrow8) * 8;   // pre-swizzled source k-offset (elements)
  int ra = l & 31, kb = (l >> 5) * 8;
  int colw = w * 32 + ra;

  for (int it = 0; it < 8; ++it) {
    int k0 = it * 64;
    __syncthreads();
    if (w < 4) {
      int row = 8 * w + lrow8;
      gload16(inpb + (size_t)(r0 + row) * KIN + k0 + koffB, ldsA + w * 1024);
    }
#pragma unroll
    for (int qi = 0; qi < 4; ++qi) {
      int q = 4 * w + qi;
      int c = 8 * q + lrow8;
      gload16(Wt + (size_t)c * KIN + k0 + koffB, ldsW + q * 1024);
    }
    __syncthreads();
    s16x8 av[4], bv[4];
#pragma unroll
    for (int kf = 0; kf < 4; ++kf) {
      int kk2 = (kf * 16 + kb) * 2;
      av[kf] = *(const s16x8*)(ldsA + ra * 128 + (kk2 ^ ((ra & 7) << 4)));
      bv[kf] = *(const s16x8*)(ldsW + colw * 128 + (kk2 ^ ((colw & 7) << 4)));
    }
#pragma unroll
    for (int kf = 0; kf < 4; ++kf) acc = mfma32(av[kf], bv[kf], acc);
  }

  float a1 = a_vec[colw], a2 = a_vec[256 + colw];
  int rquad = (l >> 5) * 4;
#pragma unroll
  for (int g = 0; g < 4; ++g) {
    int jj = r0 + g * 8 + rquad;        // 4-aligned, same 16-group for jj..jj+3
    unsigned h0 = f2bf(acc[g * 4 + 0]), h1 = f2bf(acc[g * 4 + 1]);
    unsigned h2 = f2bf(acc[g * 4 + 2]), h3 = f2bf(acc[g * 4 + 3]);
    u32x2 pk;
    pk[0] = h0 | (h1 << 16);
    pk[1] = h2 | (h3 << 16);
    *(u32x2*)(Hj + ((size_t)(jj >> 4)) * 4096 + colw * 16 + (jj & 15)) = pk;
  }
#pragma unroll
  for (int g = 0; g < 16; ++g) {
    float vs = acc[g] * a1;
    float vn = acc[g] * a2;
#pragma unroll
    for (int m = 1; m <= 16; m <<= 1) {
      vs += __shfl_xor(vs, m, 64);
      vn += __shfl_xor(vn, m, 64);
    }
    if ((l & 31) == 0) {
      int row = (g & 3) + 8 * (g >> 2) + rquad;
      red[row * 8 + w] = vs;
      red[256 + row * 8 + w] = vn;
    }
  }
  __syncthreads();
  if (tid < 32) {
    float s = 0.f, n2 = 0.f;
#pragma unroll
    for (int i = 0; i < 8; ++i) { s += red[tid * 8 + i]; n2 += red[256 + tid * 8 + i]; }
    E[r0 + tid]   = expf(s);
    E5[r0 + tid]  = expf(0.2f * s);
    Fv[r0 + tid]  = expf(n2);
    F5v[r0 + tid] = expf(0.2f * n2);
  }
}

// ---------------- fused masked-softmax @ h: phase-aligned dataflow --------------
// 256 blocks x 32 rows, 512 threads, 8 waves. Wave w takes j-tiles t = w + 8*i
// (STRIDE-8 INTERLEAVE, i = 0..63): at any instant every wave on the chip reads
// the same ~32KB window of Hj -> B-loads are L2 hits after one cold read per
// XCD (kills the 1 GB L3 re-read stream that bound R2-R7). adj is the only HBM
// stream: per tile 2 per-lane i32x4 loads (row = l&31, slice kh=(l>>5)*8; lanes
// l,l+32 consume full 64B lines), read once chip-wide. P A-frag built in regs
// (bit-exact R5/R7 construction); 8 coalesced 1KB B-loads; 8 MFMA into
// acc[8 feat-groups]. No LDS/barriers in the loop; depth-2 rolling prefetch
// (2 named sets, unroll-2, static). Epilogue: cross-wave acc+rowsum reduce via
// LDS, normalize, ELU, store.
__global__ __launch_bounds__(512) void k_phase2(const int* __restrict__ adj,
                                                const unsigned short* __restrict__ Hj,
                                                const float* __restrict__ E,
                                                const float* __restrict__ E5,
                                                const float* __restrict__ Fv,
                                                const float* __restrict__ F5v,
                                                float* __restrict__ out) {
  __shared__ __align__(16) float ldsRed[8][1024];   // 32 KB
  __shared__ float ldsS[8][32];
  __shared__ float ldsInv[32];

  const int tid = threadIdx.x, w = tid >> 6, l = tid & 63;
  const int r0 = blockIdx.x * 32;
  const int row = l & 31;
  const int kh = (l >> 5) * 8;
  const float Er = E[r0 + row], E5r = E5[r0 + row];

  const int*            __restrict__ adjR = adj + (size_t)(r0 + row) * N + kh;
  const float*          __restrict__ FvR  = Fv  + kh;
  const float*          __restrict__ GvR  = F5v + kh;
  const unsigned short* __restrict__ HjR  = Hj + row * 16 + kh;

  f32x16 acc[8];
#pragma unroll
  for (int fg = 0; fg < 8; ++fg)
#pragma unroll
    for (int i = 0; i < 16; ++i) acc[fg][i] = 0.f;
  float s_part = 0.f;

  i32x4 adA0, adA1, adB0, adB1;
  f32x4 fA0, fA1, gA0, gA1, fB0, fB1, gB0, gB1;

  // wave w's i-th tile is global tile (w + 8*i); I below is i (0..63).
#define LOADSET(S, I)                                                          \
  { const int jo = (w + 8 * (I)) * 16;                                         \
    ad##S##0 = *(const i32x4*)(adjR + jo);                                     \
    ad##S##1 = *(const i32x4*)(adjR + jo + 4);                                 \
    f##S##0  = *(const f32x4*)(FvR + jo);                                      \
    f##S##1  = *(const f32x4*)(FvR + jo + 4);                                  \
    g##S##0  = *(const f32x4*)(GvR + jo);                                      \
    g##S##1  = *(const f32x4*)(GvR + jo + 4); }

#define TILE(S, I)                                                             \
  { const int i = (I);                                                         \
    const unsigned short* hb = HjR + (size_t)(w + 8 * i) * 4096;               \
    /* P-gen from set S (loaded 2 tiles ago) */                                \
    float p0 = (ad##S##0[0] != 0) ? fmaxf(Er * f##S##0[0], E5r * g##S##0[0]) : 0.f; \
    float p1 = (ad##S##0[1] != 0) ? fmaxf(Er * f##S##0[1], E5r * g##S##0[1]) : 0.f; \
    float p2 = (ad##S##0[2] != 0) ? fmaxf(Er * f##S##0[2], E5r * g##S##0[2]) : 0.f; \
    float p3 = (ad##S##0[3] != 0) ? fmaxf(Er * f##S##0[3], E5r * g##S##0[3]) : 0.f; \
    float p4 = (ad##S##1[0] != 0) ? fmaxf(Er * f##S##1[0], E5r * g##S##1[0]) : 0.f; \
    float p5 = (ad##S##1[1] != 0) ? fmaxf(Er * f##S##1[1], E5r * g##S##1[1]) : 0.f; \
    float p6 = (ad##S##1[2] != 0) ? fmaxf(Er * f##S##1[2], E5r * g##S##1[2]) : 0.f; \
    float p7 = (ad##S##1[3] != 0) ? fmaxf(Er * f##S##1[3], E5r * g##S##1[3]) : 0.f; \
    s_part += ((p0 + p1) + (p2 + p3)) + ((p4 + p5) + (p6 + p7));               \
    u32x4 pk;                                                                  \
    pk[0] = cvtpk(p0, p1); pk[1] = cvtpk(p2, p3);                              \
    pk[2] = cvtpk(p4, p5); pk[3] = cvtpk(p6, p7);                              \
    const s16x8 aF = __builtin_bit_cast(s16x8, pk);                            \
    /* reload set S for tile i+2 (wraps harmlessly at the tail) */             \
    LOADSET(S, (i + 2) & 63)                                                   \
    _Pragma("unroll")                                                          \
    for (int fg = 0; fg < 8; ++fg) {                                           \
      s16x8 b = *(const s16x8*)(hb + fg * 512);                                \
      acc[fg] = mfma32(aF, b, acc[fg]);                                        \
    }                                                                          \
  }

  LOADSET(A, 0)
  LOADSET(B, 1)
  for (int ito = 0; ito < 32; ++ito) {
    TILE(A, ito * 2)
    TILE(B, ito * 2 + 1)
  }
#undef TILE
#undef LOADSET

  // ---- epilogue: rowsum across kh-halves + waves, then acc reduce + ELU ----
  float s2 = s_part + __shfl_xor(s_part, 32, 64);
  if (l < 32) ldsS[w][l] = s2;
  __syncthreads();
  if (tid < 32) {
    float s = 0.f;
#pragma unroll
    for (int i = 0; i < 8; ++i) s += ldsS[i][tid];
    ldsInv[tid] = 1.f / s;
  }
  __syncthreads();
#pragma unroll
  for (int sfg = 0; sfg < 8; ++sfg) {
#pragma unroll
    for (int i4 = 0; i4 < 4; ++i4) {
      f32x4 v;
#pragma unroll
      for (int i = 0; i < 4; ++i) v[i] = acc[sfg][i4 * 4 + i];
      *(f32x4*)(&ldsRed[w][l * 16 + i4 * 4]) = v;
    }
    __syncthreads();
#pragma unroll
    for (int e2 = 0; e2 < 2; ++e2) {
      int e = tid * 2 + e2;
      float v = 0.f;
#pragma unroll
      for (int i = 0; i < 8; ++i) v += ldsRed[i][e];
      int le = e >> 4, ii = e & 15;
      int orow = (ii & 3) + 8 * (ii >> 2) + 4 * (le >> 5);
      int feat = sfg * 32 + (le & 31);
      float x = v * ldsInv[orow];
      out[(size_t)(r0 + orow) * F + feat] = x > 0.f ? x : expm1f(x);
    }
    __syncthreads();
  }
}

extern "C" void kernel_launch(void* const* d_in, const int* in_sizes, int n_in,
                              void* d_out, int out_size, void* d_ws, size_t ws_size,
                              hipStream_t stream) {
  const float* input = (const float*)d_in[0];
  const int*   adj   = (const int*)d_in[1];
  const float* W     = (const float*)d_in[2];
  const float* a     = (const float*)d_in[3];
  float* out = (float*)d_out;
  char* ws = (char*)d_ws;

  unsigned short* inpb = (unsigned short*)(ws);              // 8,388,608 B
  unsigned short* Wt   = (unsigned short*)(ws + 8388608);    //   262,144 B
  unsigned short* Hj   = (unsigned short*)(ws + 8650752);    // 4,194,304 B
  float* E    = (float*)(ws + 12845056);                     //    32,768 B
  float* E5   = (float*)(ws + 12877824);
  float* Fv   = (float*)(ws + 12910592);
  float* F5   = (float*)(ws + 12943360);

  hipLaunchKernelGGL(k_cast,   dim3(2048), dim3(256), 0, stream, input, inpb, 524288);
  hipLaunchKernelGGL(k_prep_w, dim3(64),   dim3(256), 0, stream, W, Wt);
  hipLaunchKernelGGL(k_gemm1,  dim3(256),  dim3(512), 0, stream, inpb, Wt, a, Hj, E, E5, Fv, F5);
  hipLaunchKernelGGL(k_phase2, dim3(256),  dim3(512), 0, stream, adj, Hj, E, E5, Fv, F5, out);
}

// Round 9
// 134.571 us; speedup vs baseline: 3.8642x; 1.0714x over previous
//
#include <hip/hip_runtime.h>
#include <hip/hip_bf16.h>
#include <math.h>

#define DEVI static __device__ __forceinline__

using f32x4  = __attribute__((ext_vector_type(4))) float;
using f32x16 = __attribute__((ext_vector_type(16))) float;
using s16x8  = __attribute__((ext_vector_type(8))) short;
using bf16x8 = __attribute__((ext_vector_type(8))) __bf16;
using i32x4  = __attribute__((ext_vector_type(4))) int;
using u32x2  = __attribute__((ext_vector_type(2))) unsigned int;

constexpr int N   = 8192;
constexpr int KIN = 512;
constexpr int F   = 256;

DEVI unsigned f2bf(float f) {
  unsigned u = __builtin_bit_cast(unsigned, f);
  return ((u + 0x7FFFu + ((u >> 16) & 1u)) >> 16) & 0xFFFFu;
}

DEVI unsigned cvtpk(float lo, float hi) {
  unsigned r;
  asm("v_cvt_pk_bf16_f32 %0, %1, %2" : "=v"(r) : "v"(lo), "v"(hi));
  return r;
}

DEVI f32x16 mfma32(s16x8 a, s16x8 b, f32x16 c) {
  return __builtin_amdgcn_mfma_f32_32x32x16_bf16(
      __builtin_bit_cast(bf16x8, a), __builtin_bit_cast(bf16x8, b), c, 0, 0, 0);
}

DEVI void gload16(const void* g, void* lds_uniform) {
  __builtin_amdgcn_global_load_lds(
      (const __attribute__((address_space(1))) unsigned*)g,
      (__attribute__((address_space(3))) unsigned*)lds_uniform, 16, 0, 0);
}

// ---------------- cast input f32 -> bf16 (row-major [8192][512]) ----------------
__global__ __launch_bounds__(256) void k_cast(const float* __restrict__ src,
                                              unsigned short* __restrict__ dst,
                                              int n8) {
  int t = blockIdx.x * 256 + threadIdx.x;
  if (t >= n8) return;
  const f32x4* p = (const f32x4*)(src + (size_t)t * 8);
  f32x4 v0 = p[0], v1 = p[1];
  s16x8 o;
  o[0] = (short)f2bf(v0[0]); o[1] = (short)f2bf(v0[1]);
  o[2] = (short)f2bf(v0[2]); o[3] = (short)f2bf(v0[3]);
  o[4] = (short)f2bf(v1[0]); o[5] = (short)f2bf(v1[1]);
  o[6] = (short)f2bf(v1[2]); o[7] = (short)f2bf(v1[3]);
  *(s16x8*)(dst + (size_t)t * 8) = o;
}

// ---------------- W [512][256] f32 -> Wt [256][512] bf16 (transposed) -----------
__global__ __launch_bounds__(256) void k_prep_w(const float* __restrict__ W,
                                                unsigned short* __restrict__ Wt) {
  int t = blockIdx.x * 256 + threadIdx.x;   // 16384 threads
  int c = t >> 6, k0 = (t & 63) * 8;
  s16x8 o;
#pragma unroll
  for (int i = 0; i < 8; ++i) o[i] = (short)f2bf(W[(size_t)(k0 + i) * F + c]);
  *(s16x8*)(Wt + (size_t)c * KIN + k0) = o;
}

// ---------------- h = Xbf @ Wt^T : writes Ht[256][8192] bf16 + E/E5/F/F5 --------
__global__ __launch_bounds__(512) void k_gemm1(const unsigned short* __restrict__ inpb,
                                               const unsigned short* __restrict__ Wt,
                                               const float* __restrict__ a_vec,
                                               unsigned short* __restrict__ Ht,
                                               float* __restrict__ E, float* __restrict__ E5,
                                               float* __restrict__ Fv, float* __restrict__ F5v) {
  __shared__ __align__(16) char lds[4096 + 32768 + 2048];
  char* ldsA = lds;                 // [32 rows][128 B]  (XOR-swizzled)
  char* ldsW = lds + 4096;          // [256 cols][128 B] (XOR-swizzled)
  float* red = (float*)(lds + 36864); // [2][32][8]
  int tid = threadIdx.x, w = tid >> 6, l = tid & 63;
  int r0 = blockIdx.x * 32;
  f32x16 acc;
#pragma unroll
  for (int i = 0; i < 16; ++i) acc[i] = 0.f;

  int lrow8 = l >> 3;
  int koffB = ((l & 7) ^ lrow8) * 8;   // pre-swizzled source k-offset (elements)
  int ra = l & 31, kb = (l >> 5) * 8;
  int colw = w * 32 + ra;

  for (int it = 0; it < 8; ++it) {
    int k0 = it * 64;
    __syncthreads();
    if (w < 4) {
      int row = 8 * w + lrow8;
      gload16(inpb + (size_t)(r0 + row) * KIN + k0 + koffB, ldsA + w * 1024);
    }
#pragma unroll
    for (int qi = 0; qi < 4; ++qi) {
      int q = 4 * w + qi;
      int c = 8 * q + lrow8;
      gload16(Wt + (size_t)c * KIN + k0 + koffB, ldsW + q * 1024);
    }
    __syncthreads();
    s16x8 av[4], bv[4];
#pragma unroll
    for (int kf = 0; kf < 4; ++kf) {
      int kk2 = (kf * 16 + kb) * 2;
      av[kf] = *(const s16x8*)(ldsA + ra * 128 + (kk2 ^ ((ra & 7) << 4)));
      bv[kf] = *(const s16x8*)(ldsW + colw * 128 + (kk2 ^ ((colw & 7) << 4)));
    }
#pragma unroll
    for (int kf = 0; kf < 4; ++kf) acc = mfma32(av[kf], bv[kf], acc);
  }

  float a1 = a_vec[colw], a2 = a_vec[256 + colw];
  int rquad = (l >> 5) * 4;
#pragma unroll
  for (int g = 0; g < 4; ++g) {
    int rowb = g * 8 + rquad;
    unsigned h0 = f2bf(acc[g * 4 + 0]), h1 = f2bf(acc[g * 4 + 1]);
    unsigned h2 = f2bf(acc[g * 4 + 2]), h3 = f2bf(acc[g * 4 + 3]);
    u32x2 pk;
    pk[0] = h0 | (h1 << 16);
    pk[1] = h2 | (h3 << 16);
    *(u32x2*)(Ht + (size_t)colw * N + r0 + rowb) = pk;
  }
#pragma unroll
  for (int g = 0; g < 16; ++g) {
    float vs = acc[g] * a1;
    float vn = acc[g] * a2;
#pragma unroll
    for (int m = 1; m <= 16; m <<= 1) {
      vs += __shfl_xor(vs, m, 64);
      vn += __shfl_xor(vn, m, 64);
    }
    if ((l & 31) == 0) {
      int row = (g & 3) + 8 * (g >> 2) + rquad;
      red[row * 8 + w] = vs;
      red[256 + row * 8 + w] = vn;
    }
  }
  __syncthreads();
  if (tid < 32) {
    float s = 0.f, n2 = 0.f;
#pragma unroll
    for (int i = 0; i < 8; ++i) { s += red[tid * 8 + i]; n2 += red[256 + tid * 8 + i]; }
    E[r0 + tid]   = expf(s);
    E5[r0 + tid]  = expf(0.2f * s);
    Fv[r0 + tid]  = expf(n2);
    F5v[r0 + tid] = expf(0.2f * n2);
  }
}

// ---------------- fused masked-softmax-numerator @ h: 2 blocks/CU ---------------
// grid 512 = 256 row-blocks (32 rows) x KSPLIT=2 (j halves); 512 threads, 8 waves.
// R2/R6-proven skeleton: double-buffered ldsH ([256 feats][64 j]) + ldsP
// ([32 rows][64 j]), depth-1 reg prefetch of adj/F/G, counted vmcnt(3), one
// s_barrier per iter. Sized for TWO blocks per CU (LDS 72KB, <=128 regs via
// launch_bounds(512,4)): cross-block wave overlap absorbs the barrier/latency
// bubbles that pinned R2-R8 at >=2200 cy/iter with 1 block/CU (m114 mechanism).
// Wave w consumes feats w*32..+31 (single f32x16 acc = 16 AGPR). adj read once
// chip-wide (KSPLIT partitions j). Epilogue: split-K partial acc + rowsum.
__global__ __launch_bounds__(512, 4) void k_phase2(const int* __restrict__ adj,
                                                   const unsigned short* __restrict__ Ht,
                                                   const float* __restrict__ E,
                                                   const float* __restrict__ E5,
                                                   const float* __restrict__ Fv,
                                                   const float* __restrict__ F5v,
                                                   float* __restrict__ pacc,
                                                   float* __restrict__ ps) {
  __shared__ __align__(16) char lds[65536 + 8192];
  char* ldsH = lds;            // 2 x [256 feats][64 j] bf16, swizzled (32KB each)
  char* ldsP = lds + 65536;    // 2 x [32 rows][64 j] bf16, swizzled (4KB each)

  const int tid = threadIdx.x, w = tid >> 6, l = tid & 63;
  const int rb = blockIdx.x >> 1, ks = blockIdx.x & 1;
  const int r0 = rb * 32;
  const int jb = ks * 4096;

  // producer role: thread covers row r, j = it*64 + cch*4 .. +3
  const int r = tid >> 4, cch = tid & 15;
  const float Er = E[r0 + r], E5r = E5[r0 + r];
  float s_part = 0.f;
  const int*   __restrict__ adjR = adj + (size_t)(r0 + r) * N + jb + cch * 4;
  const float* __restrict__ FvR  = Fv  + jb + cch * 4;
  const float* __restrict__ GvR  = F5v + jb + cch * 4;
  const int pw_byte = r * 128 + ((cch * 8) ^ ((r & 7) << 4));

  // staging / consumer addressing
  const int lrow8 = l >> 3;
  const int koffB = ((l & 7) ^ lrow8) * 8;   // pre-swizzled source offset (elems)
  const int ra = l & 31;
  const int kb = (l >> 5) * 8;
  const int colw = w * 32 + (l & 31);

  f32x16 acc;
#pragma unroll
  for (int i = 0; i < 16; ++i) acc[i] = 0.f;

  // ---- prologue: pf(it=0) [3 VMEM] + stage H(0) into buf 0 [4 gload_lds] ----
  i32x4 ad = *(const i32x4*)(adjR);
  f32x4 fc = *(const f32x4*)(FvR);
  f32x4 gc = *(const f32x4*)(GvR);
#pragma unroll
  for (int qi = 0; qi < 4; ++qi) {
    int q = 4 * w + qi;
    int c = 8 * q + lrow8;
    gload16(Ht + (size_t)c * N + jb + koffB, ldsH + q * 1024);
  }

  for (int it = 0; it < 64; ++it) {
    const int cur = it & 1;
    char* Hc = ldsH + cur * 32768;
    char* Hn = ldsH + (cur ^ 1) * 32768;
    char* Pc = ldsP + cur * 4096;
    const int itn = (it + 1) & 63;
    const int jn = itn * 64;

    // pf next iter (3 VMEM loads)
    i32x4 adn = *(const i32x4*)(adjR + jn);
    f32x4 fn = *(const f32x4*)(FvR + jn);
    f32x4 gn = *(const f32x4*)(GvR + jn);

    // P-gen(it) from current regs (exact LeakyReLU-exp identity: masked max)
    {
      float p0 = (ad[0] != 0) ? fmaxf(Er * fc[0], E5r * gc[0]) : 0.f;
      float p1 = (ad[1] != 0) ? fmaxf(Er * fc[1], E5r * gc[1]) : 0.f;
      float p2 = (ad[2] != 0) ? fmaxf(Er * fc[2], E5r * gc[2]) : 0.f;
      float p3 = (ad[3] != 0) ? fmaxf(Er * fc[3], E5r * gc[3]) : 0.f;
      s_part += (p0 + p1) + (p2 + p3);
      u32x2 pk;
      pk[0] = cvtpk(p0, p1);
      pk[1] = cvtpk(p2, p3);
      *(u32x2*)(Pc + pw_byte) = pk;
    }

    // retire stage(it) [issued last iter]; leave only pf(next)=3 in flight
    asm volatile("s_waitcnt vmcnt(3) lgkmcnt(0)" ::: "memory");
    __builtin_amdgcn_s_barrier();

    // fragment reads from current buffers
    s16x8 av[4], bv[4];
#pragma unroll
    for (int kf = 0; kf < 4; ++kf) {
      int kk2 = (kf * 16 + kb) * 2;
      av[kf] = *(const s16x8*)(Pc + ra * 128 + (kk2 ^ ((ra & 7) << 4)));
      bv[kf] = *(const s16x8*)(Hc + colw * 128 + (kk2 ^ ((colw & 7) << 4)));
    }
    asm volatile("s_waitcnt lgkmcnt(0)" ::: "memory");
    __builtin_amdgcn_sched_barrier(0);

    // stage H(it+1) into Hn (safe post-barrier)
#pragma unroll
    for (int qi = 0; qi < 4; ++qi) {
      int q = 4 * w + qi;
      int c = 8 * q + lrow8;
      gload16(Ht + (size_t)c * N + jb + jn + koffB, Hn + q * 1024);
    }

    acc = mfma32(av[0], bv[0], acc);
    acc = mfma32(av[1], bv[1], acc);
    acc = mfma32(av[2], bv[2], acc);
    acc = mfma32(av[3], bv[3], acc);

    ad = adn; fc = fn; gc = gn;
  }

  // ---- epilogue: partial rowsum (16 threads/row shuffle), partial acc ----
  float s = s_part;
#pragma unroll
  for (int m = 1; m <= 8; m <<= 1) s += __shfl_xor(s, m, 64);
  if (cch == 0) ps[(size_t)ks * N + r0 + r] = s;

  float* po = pacc + (size_t)ks * N * F;
#pragma unroll
  for (int g = 0; g < 16; ++g) {
    int orow = (g & 3) + 8 * (g >> 2) + 4 * (l >> 5);
    po[(size_t)(r0 + orow) * F + colw] = acc[g];
  }
}

// ---------------- combine split-K partials, normalize, ELU ----------------------
__global__ __launch_bounds__(256) void k_combine(const float* __restrict__ pacc,
                                                 const float* __restrict__ ps,
                                                 float* __restrict__ out) {
  int t = blockIdx.x * 256 + threadIdx.x;  // 524288 threads
  size_t idx = (size_t)t * 4;
  int row = (int)(idx >> 8);
  f32x4 a0 = *(const f32x4*)(pacc + idx);
  f32x4 a1 = *(const f32x4*)(pacc + (size_t)N * F + idx);
  float inv = 1.f / (ps[row] + ps[N + row]);
  f32x4 o;
#pragma unroll
  for (int i = 0; i < 4; ++i) {
    float v = (a0[i] + a1[i]) * inv;
    o[i] = v > 0.f ? v : expm1f(v);
  }
  *(f32x4*)(out + idx) = o;
}

extern "C" void kernel_launch(void* const* d_in, const int* in_sizes, int n_in,
                              void* d_out, int out_size, void* d_ws, size_t ws_size,
                              hipStream_t stream) {
  const float* input = (const float*)d_in[0];
  const int*   adj   = (const int*)d_in[1];
  const float* W     = (const float*)d_in[2];
  const float* a     = (const float*)d_in[3];
  float* out = (float*)d_out;
  char* ws = (char*)d_ws;

  unsigned short* inpb = (unsigned short*)(ws);              // 8,388,608 B
  unsigned short* Wt   = (unsigned short*)(ws + 8388608);    //   262,144 B
  unsigned short* Ht   = (unsigned short*)(ws + 8650752);    // 4,194,304 B
  float* E    = (float*)(ws + 12845056);                     //    32,768 B
  float* E5   = (float*)(ws + 12877824);
  float* Fv   = (float*)(ws + 12910592);
  float* F5   = (float*)(ws + 12943360);
  float* ps   = (float*)(ws + 12976128);                     //    65,536 B
  float* pacc = (float*)(ws + 13041664);                     // 16,777,216 B

  hipLaunchKernelGGL(k_cast,   dim3(2048), dim3(256), 0, stream, input, inpb, 524288);
  hipLaunchKernelGGL(k_prep_w, dim3(64),   dim3(256), 0, stream, W, Wt);
  hipLaunchKernelGGL(k_gemm1,  dim3(256),  dim3(512), 0, stream, inpb, Wt, a, Ht, E, E5, Fv, F5);
  hipLaunchKernelGGL(k_phase2, dim3(512),  dim3(512), 0, stream, adj, Ht, E, E5, Fv, F5, pacc, ps);
  hipLaunchKernelGGL(k_combine,dim3(2048), dim3(256), 0, stream, pacc, ps, out);
}

// Round 10
// 117.302 us; speedup vs baseline: 4.4332x; 1.1472x over previous
//
#include <hip/hip_runtime.h>
#include <hip/hip_bf16.h>
#include <math.h>

#define DEVI static __device__ __forceinline__

using f32x4  = __attribute__((ext_vector_type(4))) float;
using f32x16 = __attribute__((ext_vector_type(16))) float;
using s16x8  = __attribute__((ext_vector_type(8))) short;
using bf16x8 = __attribute__((ext_vector_type(8))) __bf16;
using i32x4  = __attribute__((ext_vector_type(4))) int;
using u32x2  = __attribute__((ext_vector_type(2))) unsigned int;
using u32x4  = __attribute__((ext_vector_type(4))) unsigned int;

constexpr int N   = 8192;
constexpr int KIN = 512;
constexpr int F   = 256;

DEVI unsigned f2bf(float f) {
  unsigned u = __builtin_bit_cast(unsigned, f);
  return ((u + 0x7FFFu + ((u >> 16) & 1u)) >> 16) & 0xFFFFu;
}

DEVI float bfLO(unsigned u) { return __builtin_bit_cast(float, (u & 0xFFFFu) << 16); }
DEVI float bfHI(unsigned u) { return __builtin_bit_cast(float, u & 0xFFFF0000u); }

DEVI unsigned cvtpk(float lo, float hi) {
  unsigned r;
  asm("v_cvt_pk_bf16_f32 %0, %1, %2" : "=v"(r) : "v"(lo), "v"(hi));
  return r;
}

DEVI f32x16 mfma32(s16x8 a, s16x8 b, f32x16 c) {
  return __builtin_amdgcn_mfma_f32_32x32x16_bf16(
      __builtin_bit_cast(bf16x8, a), __builtin_bit_cast(bf16x8, b), c, 0, 0, 0);
}

DEVI void gload16(const void* g, void* lds_uniform) {
  __builtin_amdgcn_global_load_lds(
      (const __attribute__((address_space(1))) unsigned*)g,
      (__attribute__((address_space(3))) unsigned*)lds_uniform, 16, 0, 0);
}

// ---------------- cast input f32 -> bf16 (row-major [8192][512]) ----------------
__global__ __launch_bounds__(256) void k_cast(const float* __restrict__ src,
                                              unsigned short* __restrict__ dst,
                                              int n8) {
  int t = blockIdx.x * 256 + threadIdx.x;
  if (t >= n8) return;
  const f32x4* p = (const f32x4*)(src + (size_t)t * 8);
  f32x4 v0 = p[0], v1 = p[1];
  s16x8 o;
  o[0] = (short)f2bf(v0[0]); o[1] = (short)f2bf(v0[1]);
  o[2] = (short)f2bf(v0[2]); o[3] = (short)f2bf(v0[3]);
  o[4] = (short)f2bf(v1[0]); o[5] = (short)f2bf(v1[1]);
  o[6] = (short)f2bf(v1[2]); o[7] = (short)f2bf(v1[3]);
  *(s16x8*)(dst + (size_t)t * 8) = o;
}

// ---------------- W [512][256] f32 -> Wt [256][512] bf16 (transposed) -----------
__global__ __launch_bounds__(256) void k_prep_w(const float* __restrict__ W,
                                                unsigned short* __restrict__ Wt) {
  int t = blockIdx.x * 256 + threadIdx.x;   // 16384 threads
  int c = t >> 6, k0 = (t & 63) * 8;
  s16x8 o;
#pragma unroll
  for (int i = 0; i < 8; ++i) o[i] = (short)f2bf(W[(size_t)(k0 + i) * F + c]);
  *(s16x8*)(Wt + (size_t)c * KIN + k0) = o;
}

// ---------------- h = Xbf @ Wt^T : writes Ht[256][8192] bf16 + E/E5/FG ----------
__global__ __launch_bounds__(512) void k_gemm1(const unsigned short* __restrict__ inpb,
                                               const unsigned short* __restrict__ Wt,
                                               const float* __restrict__ a_vec,
                                               unsigned short* __restrict__ Ht,
                                               float* __restrict__ E, float* __restrict__ E5,
                                               unsigned* __restrict__ FG) {
  __shared__ __align__(16) char lds[4096 + 32768 + 2048];
  char* ldsA = lds;                 // [32 rows][128 B]  (XOR-swizzled)
  char* ldsW = lds + 4096;          // [256 cols][128 B] (XOR-swizzled)
  float* red = (float*)(lds + 36864); // [2][32][8]
  int tid = threadIdx.x, w = tid >> 6, l = tid & 63;
  int r0 = blockIdx.x * 32;
  f32x16 acc;
#pragma unroll
  for (int i = 0; i < 16; ++i) acc[i] = 0.f;

  int lrow8 = l >> 3;
  int koffB = ((l & 7) ^ lrow8) * 8;   // pre-swizzled source k-offset (elements)
  int ra = l & 31, kb = (l >> 5) * 8;
  int colw = w * 32 + ra;

  for (int it = 0; it < 8; ++it) {
    int k0 = it * 64;
    __syncthreads();
    if (w < 4) {
      int row = 8 * w + lrow8;
      gload16(inpb + (size_t)(r0 + row) * KIN + k0 + koffB, ldsA + w * 1024);
    }
#pragma unroll
    for (int qi = 0; qi < 4; ++qi) {
      int q = 4 * w + qi;
      int c = 8 * q + lrow8;
      gload16(Wt + (size_t)c * KIN + k0 + koffB, ldsW + q * 1024);
    }
    __syncthreads();
    s16x8 av[4], bv[4];
#pragma unroll
    for (int kf = 0; kf < 4; ++kf) {
      int kk2 = (kf * 16 + kb) * 2;
      av[kf] = *(const s16x8*)(ldsA + ra * 128 + (kk2 ^ ((ra & 7) << 4)));
      bv[kf] = *(const s16x8*)(ldsW + colw * 128 + (kk2 ^ ((colw & 7) << 4)));
    }
#pragma unroll
    for (int kf = 0; kf < 4; ++kf) acc = mfma32(av[kf], bv[kf], acc);
  }

  float a1 = a_vec[colw], a2 = a_vec[256 + colw];
  int rquad = (l >> 5) * 4;
#pragma unroll
  for (int g = 0; g < 4; ++g) {
    int rowb = g * 8 + rquad;
    unsigned h0 = f2bf(acc[g * 4 + 0]), h1 = f2bf(acc[g * 4 + 1]);
    unsigned h2 = f2bf(acc[g * 4 + 2]), h3 = f2bf(acc[g * 4 + 3]);
    u32x2 pk;
    pk[0] = h0 | (h1 << 16);
    pk[1] = h2 | (h3 << 16);
    *(u32x2*)(Ht + (size_t)colw * N + r0 + rowb) = pk;
  }
#pragma unroll
  for (int g = 0; g < 16; ++g) {
    float vs = acc[g] * a1;
    float vn = acc[g] * a2;
#pragma unroll
    for (int m = 1; m <= 16; m <<= 1) {
      vs += __shfl_xor(vs, m, 64);
      vn += __shfl_xor(vn, m, 64);
    }
    if ((l & 31) == 0) {
      int row = (g & 3) + 8 * (g >> 2) + rquad;
      red[row * 8 + w] = vs;
      red[256 + row * 8 + w] = vn;
    }
  }
  __syncthreads();
  if (tid < 32) {
    float s = 0.f, n2 = 0.f;
#pragma unroll
    for (int i = 0; i < 8; ++i) { s += red[tid * 8 + i]; n2 += red[256 + tid * 8 + i]; }
    E[r0 + tid]  = expf(s);
    E5[r0 + tid] = expf(0.2f * s);
    FG[r0 + tid] = f2bf(expf(n2)) | (f2bf(expf(0.2f * n2)) << 16);
  }
}

// ---------------- fused masked-softmax-numerator @ h: BM=64, KSPLIT=4 -----------
// grid 512 = 128 row-blocks (64 rows) x 4 j-quarters; 512 threads, 8 waves
// (wave = (rg = w>>2) row-half x (fg = w&3) 64-feat group; 2 f32x16 acc).
// LDS 73.7KB (dbuf H 2x32KB + single P 8KB) -> TWO blocks/CU; per iter: produce
// P (adj + packed-bf16 F/G, depth-1 reg pf), vmcnt(4)+bar, stage H(it+1),
// consume (12 ds_read + 8 MFMA), bar. 32 iters of BK=64 j. Ht L2/L3 traffic =
// 512 blocks x 1MB = 512MB (R2-level) at R9-level residency. Partials in bf16
// (error normalized away by rowsum) -> pacc 16MB aliased over dead inpb/Wt.
__global__ __launch_bounds__(512, 4) void k_phase2(const int* __restrict__ adj,
                                                   const unsigned short* __restrict__ Ht,
                                                   const float* __restrict__ E,
                                                   const float* __restrict__ E5,
                                                   const unsigned* __restrict__ FG,
                                                   unsigned short* __restrict__ pacc,
                                                   float* __restrict__ ps) {
  __shared__ __align__(16) char lds[65536 + 8192];
  char* ldsH = lds;            // 2 x [256 feats][64 j] bf16, swizzled (32KB each)
  char* ldsP = lds + 65536;    // 1 x [64 rows][64 j] bf16, swizzled (8KB)

  const int tid = threadIdx.x, w = tid >> 6, l = tid & 63;
  const int rb = blockIdx.x >> 2, ks = blockIdx.x & 3;
  const int r0 = rb * 64;
  const int jb = ks * 2048;

  // producer role: thread covers row r, j = it*64 + jc8 .. +7
  const int r = tid >> 3, jc8 = (tid & 7) * 8;
  const float Er = E[r0 + r], E5r = E5[r0 + r];
  float s_part = 0.f;
  const int*      __restrict__ adjR = adj + (size_t)(r0 + r) * N + jb + jc8;
  const unsigned* __restrict__ fgR  = FG + jb + jc8;
  const int pw_byte = r * 128 + ((jc8 * 2) ^ ((r & 7) << 4));

  // staging / consumer addressing
  const int lrow8 = l >> 3;
  const int koffB = ((l & 7) ^ lrow8) * 8;   // pre-swizzled source offset (elems)
  const int rg = w >> 2, fg = w & 3;
  const int ra = rg * 32 + (l & 31);
  const int khb = (l >> 5) * 16;             // k-half byte offset
  const int col0 = fg * 64 + (l & 31);
  const int col1 = col0 + 32;
  const int swz = (l & 7) << 4;

  f32x16 acc0, acc1;
#pragma unroll
  for (int i = 0; i < 16; ++i) { acc0[i] = 0.f; acc1[i] = 0.f; }

  // ---- prologue: pf(it=0) [4 VMEM] + stage H(0) into buf 0 [4 gload_lds] ----
  i32x4 ad0 = *(const i32x4*)(adjR);
  i32x4 ad1 = *(const i32x4*)(adjR + 4);
  u32x4 fgc0 = *(const u32x4*)(fgR);
  u32x4 fgc1 = *(const u32x4*)(fgR + 4);
#pragma unroll
  for (int qi = 0; qi < 4; ++qi) {
    int q = 4 * w + qi;
    int c = 8 * q + lrow8;
    gload16(Ht + (size_t)c * N + jb + koffB, ldsH + q * 1024);
  }

  for (int it = 0; it < 32; ++it) {
    char* Hc = ldsH + (it & 1) * 32768;
    char* Hn = ldsH + ((it & 1) ^ 1) * 32768;
    const int itn = (it + 1) & 31;
    const int jn = itn * 64;

    // pf next iter (4 VMEM loads)
    i32x4 nad0 = *(const i32x4*)(adjR + jn);
    i32x4 nad1 = *(const i32x4*)(adjR + jn + 4);
    u32x4 nfg0 = *(const u32x4*)(fgR + jn);
    u32x4 nfg1 = *(const u32x4*)(fgR + jn + 4);

    // P-gen(it): p = adj ? max(Er*F, E5r*G) : 0   (exact LeakyReLU-exp identity)
    {
      float p0 = (ad0[0] != 0) ? fmaxf(Er * bfLO(fgc0[0]), E5r * bfHI(fgc0[0])) : 0.f;
      float p1 = (ad0[1] != 0) ? fmaxf(Er * bfLO(fgc0[1]), E5r * bfHI(fgc0[1])) : 0.f;
      float p2 = (ad0[2] != 0) ? fmaxf(Er * bfLO(fgc0[2]), E5r * bfHI(fgc0[2])) : 0.f;
      float p3 = (ad0[3] != 0) ? fmaxf(Er * bfLO(fgc0[3]), E5r * bfHI(fgc0[3])) : 0.f;
      float p4 = (ad1[0] != 0) ? fmaxf(Er * bfLO(fgc1[0]), E5r * bfHI(fgc1[0])) : 0.f;
      float p5 = (ad1[1] != 0) ? fmaxf(Er * bfLO(fgc1[1]), E5r * bfHI(fgc1[1])) : 0.f;
      float p6 = (ad1[2] != 0) ? fmaxf(Er * bfLO(fgc1[2]), E5r * bfHI(fgc1[2])) : 0.f;
      float p7 = (ad1[3] != 0) ? fmaxf(Er * bfLO(fgc1[3]), E5r * bfHI(fgc1[3])) : 0.f;
      s_part += ((p0 + p1) + (p2 + p3)) + ((p4 + p5) + (p6 + p7));
      u32x4 pk;
      pk[0] = cvtpk(p0, p1); pk[1] = cvtpk(p2, p3);
      pk[2] = cvtpk(p4, p5); pk[3] = cvtpk(p6, p7);
      *(u32x4*)(ldsP + pw_byte) = pk;
    }

    // retire stage(it); keep only pf(it+1)=4 in flight; P write visible
    asm volatile("s_waitcnt vmcnt(4) lgkmcnt(0)" ::: "memory");
    __builtin_amdgcn_s_barrier();

    // stage H(it+1) into Hn (safe: Hn's readers drained at the barrier 1 iter ago)
#pragma unroll
    for (int qi = 0; qi < 4; ++qi) {
      int q = 4 * w + qi;
      int c = 8 * q + lrow8;
      gload16(Ht + (size_t)c * N + jb + jn + koffB, Hn + q * 1024);
    }

    // consume P + H(it)
#pragma unroll
    for (int kt = 0; kt < 4; ++kt) {
      int kk2 = kt * 32 + khb;
      s16x8 av = *(const s16x8*)(ldsP + ra * 128 + (kk2 ^ swz));
      s16x8 b0 = *(const s16x8*)(Hc + col0 * 128 + (kk2 ^ swz));
      s16x8 b1 = *(const s16x8*)(Hc + col1 * 128 + (kk2 ^ swz));
      acc0 = mfma32(av, b0, acc0);
      acc1 = mfma32(av, b1, acc1);
    }

    // all P/Hc reads complete before next produce overwrites P
    asm volatile("s_waitcnt lgkmcnt(0)" ::: "memory");
    __builtin_amdgcn_s_barrier();

    ad0 = nad0; ad1 = nad1; fgc0 = nfg0; fgc1 = nfg1;
  }

  // ---- epilogue: partial rowsum (8 threads/row), bf16 partial acc ----
  float s = s_part;
#pragma unroll
  for (int m = 1; m <= 4; m <<= 1) s += __shfl_xor(s, m, 64);
  if ((tid & 7) == 0) ps[(size_t)ks * N + r0 + r] = s;

  unsigned short* po = pacc + (size_t)ks * N * F;
#pragma unroll
  for (int g = 0; g < 16; ++g) {
    int orow = rg * 32 + (g & 3) + 8 * (g >> 2) + 4 * (l >> 5);
    po[(size_t)(r0 + orow) * F + col0] = (unsigned short)f2bf(acc0[g]);
    po[(size_t)(r0 + orow) * F + col1] = (unsigned short)f2bf(acc1[g]);
  }
}

// ---------------- combine 4 bf16 split-K partials, normalize, ELU ---------------
__global__ __launch_bounds__(256) void k_combine(const unsigned short* __restrict__ pacc,
                                                 const float* __restrict__ ps,
                                                 float* __restrict__ out) {
  int t = blockIdx.x * 256 + threadIdx.x;  // 524288 threads, 4 feats each
  size_t idx = (size_t)t * 4;
  int row = (int)(idx >> 8);
  f32x4 sum;
#pragma unroll
  for (int i = 0; i < 4; ++i) sum[i] = 0.f;
#pragma unroll
  for (int k = 0; k < 4; ++k) {
    u32x2 q = *(const u32x2*)(pacc + (size_t)k * N * F + idx);
    sum[0] += bfLO(q[0]) * 1.f; sum[1] += bfHI(q[0]);
    sum[2] += bfLO(q[1]);       sum[3] += bfHI(q[1]);
  }
  float inv = 1.f / (ps[row] + ps[N + row] + ps[2 * N + row] + ps[3 * N + row]);
  f32x4 o;
#pragma unroll
  for (int i = 0; i < 4; ++i) {
    float v = sum[i] * inv;
    o[i] = v > 0.f ? v : expm1f(v);
  }
  *(f32x4*)(out + idx) = o;
}

extern "C" void kernel_launch(void* const* d_in, const int* in_sizes, int n_in,
                              void* d_out, int out_size, void* d_ws, size_t ws_size,
                              hipStream_t stream) {
  const float* input = (const float*)d_in[0];
  const int*   adj   = (const int*)d_in[1];
  const float* W     = (const float*)d_in[2];
  const float* a     = (const float*)d_in[3];
  float* out = (float*)d_out;
  char* ws = (char*)d_ws;

  // pacc (16 MB, bf16) aliases inpb+Wt: both dead before k_phase2 runs.
  unsigned short* pacc = (unsigned short*)(ws);              // 16,777,216 B @0
  unsigned short* inpb = (unsigned short*)(ws);              //  8,388,608 B @0
  unsigned short* Wt   = (unsigned short*)(ws + 8388608);    //    262,144 B
  unsigned short* Ht   = (unsigned short*)(ws + 16777216);   //  4,194,304 B
  float*    E  = (float*)(ws + 20971520);                    //     32,768 B
  float*    E5 = (float*)(ws + 21004288);                    //     32,768 B
  unsigned* FG = (unsigned*)(ws + 21037056);                 //     32,768 B
  float*    ps = (float*)(ws + 21069824);                    //    131,072 B -> 21.2 MB

  hipLaunchKernelGGL(k_cast,   dim3(2048), dim3(256), 0, stream, input, inpb, 524288);
  hipLaunchKernelGGL(k_prep_w, dim3(64),   dim3(256), 0, stream, W, Wt);
  hipLaunchKernelGGL(k_gemm1,  dim3(256),  dim3(512), 0, stream, inpb, Wt, a, Ht, E, E5, FG);
  hipLaunchKernelGGL(k_phase2, dim3(512),  dim3(512), 0, stream, adj, Ht, E, E5, FG, pacc, ps);
  hipLaunchKernelGGL(k_combine,dim3(2048), dim3(256), 0, stream, pacc, ps, out);
}